// Round 6
// baseline (442.775 us; speedup 1.0000x reference)
//
#include <hip/hip_runtime.h>
#include <math.h>

#define MI 512
#define NPT 8192
#define JIT 1e-6f
#define LOG2PI 1.8378770664093453f

// ws float offsets
#define OFF_A     0         // 512x512 Kuu -> L (lower; diag blocks never read downstream)
#define OFF_LINV  262144    // 512x512 Linv^T (LT[r][c] = Linv[c][r]); upper region only
#define OFF_QS    524288    // 512x512 q_sqrt
#define OFF_QC    786432    // 512x512 q_cov (symmetric)
#define OFF_DINV  1048576   // 8 x 64x64 diag-block inverses
#define OFF_PART  1081856   // 512 partial ell sums (2 per main block)
#define OFF_FLAGS 1082368   // flags, each padded to 32 uints (128 B)
// flag ids (padded): fD=0..7, FL=8..71 (8+b*8+p), TFLG=72..135 (72+s*8+J),
//                    ROWC=136..143, GFLG=144..207 (144+b*8+p), QCC=208, PARTC=209
#define NFLAGS 211

#define FMA16(ACC,a0,a1,a2,a3,b0,b1,b2,b3) \
  ACC[0][0]+=a0*b0; ACC[0][1]+=a0*b1; ACC[0][2]+=a0*b2; ACC[0][3]+=a0*b3; \
  ACC[1][0]+=a1*b0; ACC[1][1]+=a1*b1; ACC[1][2]+=a1*b2; ACC[1][3]+=a1*b3; \
  ACC[2][0]+=a2*b0; ACC[2][1]+=a2*b1; ACC[2][2]+=a2*b2; ACC[2][3]+=a2*b3; \
  ACC[3][0]+=a3*b0; ACC[3][1]+=a3*b1; ACC[3][2]+=a3*b2; ACC[3][3]+=a3*b3;

__device__ __forceinline__ void wait_flag(unsigned* f, int tid) {
  if (tid == 0) {
    while (__hip_atomic_load(f, __ATOMIC_RELAXED, __HIP_MEMORY_SCOPE_AGENT) == 0)
      __builtin_amdgcn_s_sleep(2);
    __builtin_amdgcn_fence(__ATOMIC_ACQUIRE, "agent");
  }
  __syncthreads();
}
__device__ __forceinline__ void wait_count(unsigned* c, unsigned tgt, int tid) {
  if (tid == 0) {
    while (__hip_atomic_load(c, __ATOMIC_RELAXED, __HIP_MEMORY_SCOPE_AGENT) < tgt)
      __builtin_amdgcn_s_sleep(2);
    __builtin_amdgcn_fence(__ATOMIC_ACQUIRE, "agent");
  }
  __syncthreads();
}
__device__ __forceinline__ void raise_flag(unsigned* f, int tid) {
  __syncthreads();
  if (tid == 0) {
    __builtin_amdgcn_fence(__ATOMIC_RELEASE, "agent");
    __hip_atomic_store(f, 1u, __ATOMIC_RELAXED, __HIP_MEMORY_SCOPE_AGENT);
  }
}
__device__ __forceinline__ void publish_tile(unsigned* f, unsigned* cnt, int tid) {
  __syncthreads();
  if (tid == 0) {
    __builtin_amdgcn_fence(__ATOMIC_RELEASE, "agent");
    __hip_atomic_store(f, 1u, __ATOMIC_RELAXED, __HIP_MEMORY_SCOPE_AGENT);
    __hip_atomic_fetch_add(cnt, 1u, __ATOMIC_RELAXED, __HIP_MEMORY_SCOPE_AGENT);
  }
}

// ---------------------------------------------------------------- prep
__global__ __launch_bounds__(256) void k_prep(const float* __restrict__ Z,
    const float* __restrict__ qlv, const float* __restrict__ lsP,
    const float* __restrict__ osP, float* __restrict__ ws) {
  int u = blockIdx.x*256 + threadIdx.x;
  if (blockIdx.x < 27) {
    int fi = blockIdx.x*256 + threadIdx.x;
    if (fi < NFLAGS*32) ((unsigned*)(ws + OFF_FLAGS))[fi] = 0u;
  }
  float ls = lsP[0], os = osP[0];
  float ils2 = 1.0f/(ls*ls);
  if (u < MI*MI) {
    int i = u >> 9, j = u & 511;
    float4 a0 = *(const float4*)(Z + i*8);
    float4 a1 = *(const float4*)(Z + i*8 + 4);
    float4 b0 = *(const float4*)(Z + j*8);
    float4 b1 = *(const float4*)(Z + j*8 + 4);
    float d0=a0.x-b0.x, d1=a0.y-b0.y, d2=a0.z-b0.z, d3=a0.w-b0.w;
    float d4=a1.x-b1.x, d5=a1.y-b1.y, d6=a1.z-b1.z, d7=a1.w-b1.w;
    float sq = d0*d0+d1*d1+d2*d2+d3*d3+d4*d4+d5*d5+d6*d6+d7*d7;
    float v = os*__expf(-0.5f*ils2*sq);
    if (i==j) v += JIT;
    ws[OFF_A + u] = v;
  } else {
    int w2 = u - MI*MI;
    if (w2 < MI*MI) {
      int i = w2 >> 9, j = w2 & 511;
      ws[OFF_QS + w2] = (j <= i) ? __expf(0.5f*qlv[w2]) : 0.0f;
    }
  }
}

// -------- fused DAG: chol(8) + linv(36) + gram(21) + main(256, 32pts 2-pass) = 321
// QC-GEMM folded into main blocks B<64 (pre-gate shadow work).
// __launch_bounds__(256, 3): co-residency trivially guaranteed (321 << slots).
__global__ __launch_bounds__(256, 3) void k_dag(const float* __restrict__ X,
    const float* __restrict__ Yv, const float* __restrict__ Z,
    const float* __restrict__ qmu, const float* __restrict__ qlv,
    const float* __restrict__ llvP, const float* __restrict__ lsP,
    const float* __restrict__ osP, float* __restrict__ ws,
    float* __restrict__ out) {
  __shared__ float SH[13340];   // 53.36 KB -> 3 blocks/CU
  float* A    = ws + OFF_A;
  float* LT   = ws + OFF_LINV;
  const float* QC = ws + OFF_QC;
  float* DINV = ws + OFF_DINV;
  float* PART = ws + OFF_PART;
  unsigned* FB = (unsigned*)(ws + OFF_FLAGS);
  #define FLA(i) (FB + (i)*32)
  int bid = blockIdx.x, tid = threadIdx.x;
  int ty4 = (tid >> 4)*4, tx4 = (tid & 15)*4;

  // ================= CHOL path ==============
  if (bid < 8) {
    __builtin_amdgcn_s_setprio(3);
    int b = bid, Rb = b*64;
    float* Dg = SH;            // [64][65] running diag tile
    float* Sa = SH + 4160;     // Dinv staging / assembly
    float* Sb = SH + 8320;     // G / Lsub staging
    float* TMP = SH + 12480;   // 816 floats
    for (int e = tid; e < 4096; e += 256)
      Dg[(e>>6)*65 + (e&63)] = A[(Rb + (e>>6))*512 + Rb + (e&63)];

    for (int p = 0; p < b; ++p) {
      if (p > 0) wait_flag(FLA(144 + b*8 + p), tid);   // helper wrote G into A(b,p)
      // stage G first (only needs gram flag), overlapping with the fD wait
      for (int e = tid; e < 4096; e += 256)
        Sb[(e>>6)*65 + (e&63)] = A[(Rb + (e>>6))*512 + p*64 + (e&63)];
      wait_flag(FLA(p), tid);                          // fD[p]
      for (int e = tid; e < 4096; e += 256)
        Sa[(e>>6)*65 + (e&63)] = DINV[p*4096 + e];
      __syncthreads();
      // TRSM: Lsub = G * Dinv_p^T
      float acc2[4][4] = {{0.f}};
      for (int m = 0; m < 64; ++m) {
        float a0=Sb[(ty4+0)*65+m],a1=Sb[(ty4+1)*65+m],a2=Sb[(ty4+2)*65+m],a3=Sb[(ty4+3)*65+m];
        float b0=Sa[(tx4+0)*65+m],b1=Sa[(tx4+1)*65+m],b2=Sa[(tx4+2)*65+m],b3=Sa[(tx4+3)*65+m];
        FMA16(acc2,a0,a1,a2,a3,b0,b1,b2,b3)
      }
      __syncthreads();
      #pragma unroll
      for (int u = 0; u < 4; ++u)
        #pragma unroll
        for (int v = 0; v < 4; ++v) {
          Sb[(ty4+u)*65 + tx4+v] = acc2[u][v];
          A[(Rb+ty4+u)*512 + p*64 + tx4+v] = acc2[u][v];
        }
      raise_flag(FLA(8 + b*8 + p), tid);
      // SYRK: Dg -= Lsub Lsub^T
      float c2[4][4] = {{0.f}};
      for (int m = 0; m < 64; ++m) {
        float a0=Sb[(ty4+0)*65+m],a1=Sb[(ty4+1)*65+m],a2=Sb[(ty4+2)*65+m],a3=Sb[(ty4+3)*65+m];
        float b0=Sb[(tx4+0)*65+m],b1=Sb[(tx4+1)*65+m],b2=Sb[(tx4+2)*65+m],b3=Sb[(tx4+3)*65+m];
        FMA16(c2,a0,a1,a2,a3,b0,b1,b2,b3)
      }
      #pragma unroll
      for (int u = 0; u < 4; ++u)
        #pragma unroll
        for (int v = 0; v < 4; ++v)
          Dg[(ty4+u)*65 + tx4+v] -= c2[u][v];
    }
    __syncthreads();

    // factor 64x64 Dg via 16-wide sub-panels; Dinv assembled into Sa
    for (int e = tid; e < 4096; e += 256) Sa[(e>>6)*65 + (e&63)] = 0.0f;
    __syncthreads();
    for (int t = 0; t < 4; ++t) {
      const int c0 = t*16;
      if (tid < 16) {
        float a[16];
        #pragma unroll
        for (int j = 0; j < 16; ++j) a[j] = Dg[(c0+tid)*65 + c0 + j];
        float rr = 0.f;
        #pragma unroll
        for (int j = 0; j < 16; ++j) {
          float d = __shfl(a[j], j);
          float r = rsqrtf(d);
          r = r*(1.5f - 0.5f*d*r*r);
          if (tid == j) rr = r;
          a[j] *= r;
          #pragma unroll
          for (int k = j+1; k < 16; ++k)
            a[k] -= a[j]*__shfl(a[j], k);
        }
        #pragma unroll
        for (int j = 0; j < 16; ++j)
          Dg[(c0+tid)*65 + c0 + j] = (j <= tid) ? a[j] : 0.0f;
        float v[16];
        #pragma unroll
        for (int i = 0; i < 16; ++i) {
          float s = (tid == i) ? 1.0f : 0.0f;
          #pragma unroll
          for (int k = 0; k < i; ++k)
            s -= Dg[(c0+i)*65 + c0 + k]*v[k];
          v[i] = s * __shfl(rr, i);
        }
        #pragma unroll
        for (int i = 0; i < 16; ++i)
          Sa[(c0+i)*65 + c0 + tid] = v[i];
      }
      __syncthreads();
      if (t < 3) {
        const int cnt = 48 - c0;
        const int r0 = c0 + 16;
        float res[3];
        int nout = cnt*16, idx = 0;
        for (int e = tid; e < nout; e += 256, ++idx) {
          int r = r0 + (e >> 4), j = e & 15;
          float s = 0.f;
          #pragma unroll
          for (int m = 0; m < 16; ++m)
            s += Dg[r*65 + c0 + m]*Sa[(c0+j)*65 + c0 + m];
          res[idx] = s;
        }
        __syncthreads();
        idx = 0;
        for (int e = tid; e < nout; e += 256, ++idx)
          Dg[(r0 + (e >> 4))*65 + c0 + (e & 15)] = res[idx];
        __syncthreads();
        for (int e = tid; e < cnt*cnt; e += 256) {
          int r = r0 + e/cnt, c = r0 + e%cnt;
          float s = 0.f;
          #pragma unroll
          for (int m = 0; m < 16; ++m)
            s += Dg[r*65 + c0 + m]*Dg[c*65 + c0 + m];
          Dg[r*65 + c] -= s;
        }
        __syncthreads();
      }
    }
    for (int d = 1; d < 4; ++d) {
      int nout = (4-d)*256;
      for (int e = tid; e < nout; e += 256) {
        int bs = e >> 8, I = bs, J = I + d;
        int i = (e >> 4) & 15, c = e & 15;
        float s = 0.f;
        for (int k = I; k < J; ++k) {
          #pragma unroll
          for (int m = 0; m < 16; ++m)
            s += Dg[(J*16+i)*65 + k*16+m]*Sa[(k*16+m)*65 + I*16+c];
        }
        TMP[bs*272 + i*17 + c] = s;
      }
      __syncthreads();
      for (int e = tid; e < nout; e += 256) {
        int bs = e >> 8, I = bs, J = I + d;
        int i = (e >> 4) & 15, c = e & 15;
        float s = 0.f;
        #pragma unroll
        for (int m = 0; m < 16; ++m)
          s += Sa[(J*16+i)*65 + J*16+m]*TMP[bs*272 + m*17 + c];
        Sa[(J*16+i)*65 + I*16+c] = -s;
      }
      __syncthreads();
    }
    for (int e = tid; e < 4096; e += 256)
      DINV[b*4096 + e] = Sa[(e>>6)*65 + (e&63)];
    raise_flag(FLA(b), tid);
    return;
  }

  // ================= LINV path (36 lower-tri tiles) ======================
  if (bid < 44) {
    __builtin_amdgcn_s_setprio(2);
    int t = bid - 8;
    int s = 0, rem = t;
    while (rem >= s+1) { rem -= (s+1); ++s; }
    int J = rem;
    if (s == J) {
      wait_flag(FLA(s), tid);
      for (int e = tid; e < 4096; e += 256) {
        int i = e >> 6, j = e & 63;
        LT[(64*s+j)*512 + 64*s + i] = DINV[s*4096 + e];
      }
      publish_tile(FLA(72 + s*8 + J), FLA(136 + s), tid);
      return;
    }
    float* Ls = SH;
    float* Vs = SH + 4160;
    float* T  = SH + 8320;
    float acc[4][4] = {{0.f}};
    for (int k = J; k < s; ++k) {
      wait_flag(FLA(72 + k*8 + J), tid);
      wait_flag(FLA(8 + s*8 + k), tid);
      for (int e = tid; e < 1024; e += 256) {
        int row = e >> 4, m4 = (e & 15)*4;
        float4 a = *(const float4*)(A + (64*s+row)*512 + 64*k + m4);
        Ls[row*65+m4+0]=a.x; Ls[row*65+m4+1]=a.y; Ls[row*65+m4+2]=a.z; Ls[row*65+m4+3]=a.w;
        float4 v = *(const float4*)(LT + (64*J+row)*512 + 64*k + m4);
        Vs[(m4+0)*65+row]=v.x; Vs[(m4+1)*65+row]=v.y; Vs[(m4+2)*65+row]=v.z; Vs[(m4+3)*65+row]=v.w;
      }
      __syncthreads();
      for (int m = 0; m < 64; ++m) {
        float a0=Ls[(ty4+0)*65+m],a1=Ls[(ty4+1)*65+m],a2=Ls[(ty4+2)*65+m],a3=Ls[(ty4+3)*65+m];
        float b0=Vs[m*65+tx4+0],b1=Vs[m*65+tx4+1],b2=Vs[m*65+tx4+2],b3=Vs[m*65+tx4+3];
        FMA16(acc,a0,a1,a2,a3,b0,b1,b2,b3)
      }
      __syncthreads();
    }
    wait_flag(FLA(s), tid);
    #pragma unroll
    for (int u = 0; u < 4; ++u)
      #pragma unroll
      for (int v = 0; v < 4; ++v)
        T[(ty4+u)*65 + tx4+v] = acc[u][v];
    for (int e = tid; e < 4096; e += 256) Ls[(e>>6)*65 + (e&63)] = DINV[s*4096 + e];
    __syncthreads();
    float acc2[4][4] = {{0.f}};
    for (int m = 0; m < 64; ++m) {
      float a0=Ls[(ty4+0)*65+m],a1=Ls[(ty4+1)*65+m],a2=Ls[(ty4+2)*65+m],a3=Ls[(ty4+3)*65+m];
      float b0=T[m*65+tx4+0],b1=T[m*65+tx4+1],b2=T[m*65+tx4+2],b3=T[m*65+tx4+3];
      FMA16(acc2,a0,a1,a2,a3,b0,b1,b2,b3)
    }
    #pragma unroll
    for (int u = 0; u < 4; ++u)
      #pragma unroll
      for (int v = 0; v < 4; ++v)
        LT[(64*J+tx4+v)*512 + 64*s+ty4+u] = -acc2[u][v];
    publish_tile(FLA(72 + s*8 + J), FLA(136 + s), tid);
    return;
  }

  // ================= GRAM helpers (21 blocks) ============================
  if (bid < 65) {
    __builtin_amdgcn_s_setprio(2);
    int hid = bid - 44;
    int b = 2, rem = hid;
    while (rem >= b-1) { rem -= (b-1); ++b; }
    int p = rem + 1;                       // 1 <= p < b
    float* Sa = SH;                        // [64][65] Lsub(b,pp)
    float* Sb = SH + 4160;                 // [64][65] Lsub(p,pp)
    float gacc[4][4] = {{0.f}};
    for (int pp = 0; pp < p; ++pp) {
      wait_flag(FLA(8 + b*8 + pp), tid);
      wait_flag(FLA(8 + p*8 + pp), tid);
      for (int e = tid; e < 4096; e += 256) {
        int row = e>>6, col = e&63;
        Sa[row*65+col] = A[(b*64+row)*512 + pp*64 + col];
        Sb[row*65+col] = A[(p*64+row)*512 + pp*64 + col];
      }
      __syncthreads();
      for (int m = 0; m < 64; ++m) {
        float a0=Sa[(ty4+0)*65+m],a1=Sa[(ty4+1)*65+m],a2=Sa[(ty4+2)*65+m],a3=Sa[(ty4+3)*65+m];
        float b0=Sb[(tx4+0)*65+m],b1=Sb[(tx4+1)*65+m],b2=Sb[(tx4+2)*65+m],b3=Sb[(tx4+3)*65+m];
        FMA16(gacc,a0,a1,a2,a3,b0,b1,b2,b3)
      }
      __syncthreads();
    }
    #pragma unroll
    for (int u = 0; u < 4; ++u)
      #pragma unroll
      for (int v = 0; v < 4; ++v)
        A[(b*64+ty4+u)*512 + p*64 + tx4+v] -= gacc[u][v];
    raise_flag(FLA(144 + b*8 + p), tid);
    return;
  }

  // ================= MAIN path (256 blocks x 32 points, 2 passes) ========
  {
    int B = bid - 65;           // 0..255
    float* KL  = SH;            // 8192: k[c][pt] stride 16
    float* PB  = SH + 8192;     // 3264: partial Lam for groups 1..3, [64][17] each
    float* FB2 = SH + 11456;    // 1280: final Lam [64][20] (float4-aligned rows)
    float* qsh = SH + 12736;    // 512
    float* Xs  = SH + 8192;     // overlay PB during KL build (128 floats)
    float* RD  = SH + 8192;     // overlay PB in final reduction (1632 floats)
    float* elli= SH + 9824;     // 16 (after RD)
    int* lastf = (int*)(SH + 13248);
    float ls = lsP[0], os = osP[0], llv = llvP[0];
    float ils2 = 1.0f/(ls*ls);

    // ---- QC duty (blocks B<64): QC = QS QS^T + JIT*I, pre-gate shadow work
    if (B < 64) {
      int bi = B >> 3, bj = B & 7;
      const float* QSp = ws + OFF_QS;
      float* QCw = ws + OFF_QC;
      float* Xs2 = SH;            // [64][20]
      float* Ys2 = SH + 1280;     // [64][20]
      int lrow = tid >> 2, lc4 = (tid & 3)*4;
      float acc[4][4] = {{0.f}};
      for (int kc = 0; kc < 512; kc += 16) {
        float4 xa = *(const float4*)(QSp + (bi*64+lrow)*512 + kc + lc4);
        float4 ya = *(const float4*)(QSp + (bj*64+lrow)*512 + kc + lc4);
        Xs2[lrow*20+lc4+0]=xa.x; Xs2[lrow*20+lc4+1]=xa.y; Xs2[lrow*20+lc4+2]=xa.z; Xs2[lrow*20+lc4+3]=xa.w;
        Ys2[lrow*20+lc4+0]=ya.x; Ys2[lrow*20+lc4+1]=ya.y; Ys2[lrow*20+lc4+2]=ya.z; Ys2[lrow*20+lc4+3]=ya.w;
        __syncthreads();
        #pragma unroll
        for (int kk = 0; kk < 16; ++kk) {
          float a0=Xs2[(ty4+0)*20+kk],a1=Xs2[(ty4+1)*20+kk],a2=Xs2[(ty4+2)*20+kk],a3=Xs2[(ty4+3)*20+kk];
          float b0=Ys2[(tx4+0)*20+kk],b1=Ys2[(tx4+1)*20+kk],b2=Ys2[(tx4+2)*20+kk],b3=Ys2[(tx4+3)*20+kk];
          FMA16(acc,a0,a1,a2,a3,b0,b1,b2,b3)
        }
        __syncthreads();
      }
      #pragma unroll
      for (int u = 0; u < 4; ++u)
        #pragma unroll
        for (int v = 0; v < 4; ++v) {
          int gi = bi*64+ty4+u, gj = bj*64+tx4+v;
          float o = acc[u][v]; if (gi==gj) o += JIT;
          QCw[gi*512+gj] = o;
        }
      __syncthreads();
      if (tid == 0) {
        __builtin_amdgcn_fence(__ATOMIC_RELEASE, "agent");
        __hip_atomic_fetch_add(FLA(208), 1u, __ATOMIC_RELAXED, __HIP_MEMORY_SCOPE_AGENT);
      }
    }

    qsh[tid] = qmu[tid]; qsh[tid+256] = qmu[tid+256];

    int gq = tid >> 6;               // c-quarter (wave id)
    int lr = (tid >> 2) & 15;        // row-group within slab (16 x 4 rows)
    int lrow4 = lr*4;
    int pq4 = (tid & 3)*4;           // point group
    int rq4 = (tid >> 2)*4;          // PV output row group (0..252)

    for (int pass = 0; pass < 2; ++pass) {
      int pbase = B*32 + pass*16;
      __syncthreads();               // protect SH+8192 region (QC/RD use) before Xs
      if (tid < 128) { int pp = tid>>3, d = tid&7; Xs[pp*8+d] = X[(pbase+pp)*8 + d]; }
      __syncthreads();
      for (int e = tid; e < 8192; e += 256) {
        int cc = e >> 4, pp = e & 15;
        float4 z0 = *(const float4*)(Z + cc*8);
        float4 z1 = *(const float4*)(Z + cc*8 + 4);
        float d0=z0.x-Xs[pp*8+0], d1=z0.y-Xs[pp*8+1], d2=z0.z-Xs[pp*8+2], d3=z0.w-Xs[pp*8+3];
        float d4=z1.x-Xs[pp*8+4], d5=z1.y-Xs[pp*8+5], d6=z1.z-Xs[pp*8+6], d7=z1.w-Xs[pp*8+7];
        float sq = d0*d0+d1*d1+d2*d2+d3*d3+d4*d4+d5*d5+d6*d6+d7*d7;
        KL[e] = os*__expf(-0.5f*ils2*sq);
      }
      if (pass == 0) wait_count(FLA(208), 64u, tid);   // QC ready (also syncs KL)
      else __syncthreads();

      float pmp[4] = {0.f,0.f,0.f,0.f}, lsp[4] = {0.f,0.f,0.f,0.f};
      float ua0[4][4] = {{0.f}}, ua1[4][4] = {{0.f}};

      for (int s = 0; s < 8; ++s) {
        if (pass == 0) wait_count(FLA(136 + s), (unsigned)(s+1), tid);
        else __syncthreads();          // order FB2 reads (prev PV) vs writes below
        // ---- Lam slab s: all 256 threads, c-range split 4 ways
        int Q = 16*(s+1);
        int cbeg = gq*Q, cend = cbeg + Q;
        float acc[4][4] = {{0.f}};
        const float* Lcol = LT + 64*s + lrow4;
        #pragma unroll 4
        for (int c = cbeg; c < cend; ++c) {
          float4 kv = *(const float4*)&KL[c*16 + pq4];
          float4 lv = *(const float4*)(Lcol + c*512);
          FMA16(acc, lv.x,lv.y,lv.z,lv.w, kv.x,kv.y,kv.z,kv.w)
        }
        if (gq > 0) {
          float* pb = PB + (gq-1)*1088;
          #pragma unroll
          for (int u = 0; u < 4; ++u)
            #pragma unroll
            for (int v = 0; v < 4; ++v)
              pb[(lrow4+u)*17 + pq4+v] = acc[u][v];
        }
        __syncthreads();
        if (gq == 0) {
          #pragma unroll
          for (int u = 0; u < 4; ++u) {
            float qv = qsh[64*s + lrow4 + u];
            #pragma unroll
            for (int v = 0; v < 4; ++v) {
              float f = acc[u][v]
                      + PB[(lrow4+u)*17 + pq4+v]
                      + PB[1088 + (lrow4+u)*17 + pq4+v]
                      + PB[2176 + (lrow4+u)*17 + pq4+v];
              FB2[(lrow4+u)*20 + pq4+v] = f;
              pmp[v] += f*qv;
              lsp[v] += f*f;
            }
          }
        }
        __syncthreads();
        // ---- PV: ua += QC[64s+cl][:] * Lam[cl][:]
        #pragma unroll 2
        for (int cl = 0; cl < 64; ++cl) {
          float4 kv = *(const float4*)&FB2[cl*20 + pq4];
          float4 q0 = *(const float4*)(QC + (64*s+cl)*512 + rq4);
          float4 q1 = *(const float4*)(QC + (64*s+cl)*512 + 256 + rq4);
          FMA16(ua0, q0.x,q0.y,q0.z,q0.w, kv.x,kv.y,kv.z,kv.w)
          FMA16(ua1, q1.x,q1.y,q1.z,q1.w, kv.x,kv.y,kv.z,kv.w)
        }
      }
      __syncthreads();  // protect PB region before RD overlay

      // ---- reductions: pm/lsq from group 0 (16 lr-groups), usq from all
      if (gq == 0) {
        #pragma unroll
        for (int v = 0; v < 4; ++v) {
          RD[lr*17 + pq4+v] = pmp[v];
          RD[272 + lr*17 + pq4+v] = lsp[v];
        }
      }
      float usq[4] = {0.f,0.f,0.f,0.f};
      #pragma unroll
      for (int u = 0; u < 4; ++u)
        #pragma unroll
        for (int v = 0; v < 4; ++v)
          usq[v] += ua0[u][v]*ua0[u][v] + ua1[u][v]*ua1[u][v];
      #pragma unroll
      for (int v = 0; v < 4; ++v)
        RD[544 + (tid>>2)*17 + pq4+v] = usq[v];
      __syncthreads();
      if (tid < 16) {
        float pm = 0.f, lq = 0.f, us = 0.f;
        for (int r2 = 0; r2 < 16; ++r2) {
          pm += RD[r2*17 + tid];
          lq += RD[272 + r2*17 + tid];
        }
        for (int r2 = 0; r2 < 64; ++r2)
          us += RD[544 + r2*17 + tid];
        int gi = pbase + tid;
        float diff = Yv[gi] - pm;
        float diagc = os + us - lq;
        float iss = __expf(-llv);
        elli[tid] = -0.5f*((diff*diff + diagc)*iss + (LOG2PI + llv));
      }
      __syncthreads();
      if (tid == 0) {
        float sum = 0.f;
        #pragma unroll
        for (int i2 = 0; i2 < 16; ++i2) sum += elli[i2];
        PART[B*2 + pass] = sum;
      }
    }

    __syncthreads();
    if (tid == 0) {
      __builtin_amdgcn_fence(__ATOMIC_RELEASE, "agent");
      unsigned old = __hip_atomic_fetch_add(FLA(209), 1u, __ATOMIC_RELAXED, __HIP_MEMORY_SCOPE_AGENT);
      lastf[0] = (old == 255u) ? 1 : 0;
    }
    __syncthreads();
    if (lastf[0]) {
      // last main block: final scalar fold
      if (tid == 0) __builtin_amdgcn_fence(__ATOMIC_ACQUIRE, "agent");
      __syncthreads();
      double* sh = (double*)SH;   // 256 doubles in the (done) KL region
      double pa = 0.0, tr = 0.0, mm = 0.0, ld = 0.0;
      for (int i = tid; i < 512; i += 256) {
        pa += (double)PART[i];
        tr += (double)QC[i*513];
        double q = (double)qmu[i]; mm += q*q;
        ld += (double)qlv[i*513];
      }
      double vals[4] = {pa, tr, mm, ld};
      double res[4];
      for (int t2 = 0; t2 < 4; ++t2) {
        sh[tid] = vals[t2]; __syncthreads();
        for (int s2 = 128; s2 > 0; s2 >>= 1) {
          if (tid < s2) sh[tid] += sh[tid+s2];
          __syncthreads();
        }
        res[t2] = sh[0]; __syncthreads();
      }
      if (tid == 0) {
        double n = 8192.0;
        double ell = res[0]/n;
        double kl = 0.5*(res[1] + res[2] - 512.0 - res[3])/n;
        out[0] = (float)(ell - kl);
      }
    }
  }
}

extern "C" void kernel_launch(void* const* d_in, const int* in_sizes, int n_in,
                              void* d_out, int out_size, void* d_ws, size_t ws_size,
                              hipStream_t stream) {
  (void)in_sizes; (void)n_in; (void)out_size; (void)ws_size;
  const float* X   = (const float*)d_in[0];
  const float* Y   = (const float*)d_in[1];
  const float* Z   = (const float*)d_in[2];
  const float* qmu = (const float*)d_in[3];
  const float* qlv = (const float*)d_in[4];
  const float* llv = (const float*)d_in[5];
  const float* ls  = (const float*)d_in[6];
  const float* os  = (const float*)d_in[7];
  float* ws = (float*)d_ws;
  float* out = (float*)d_out;

  k_prep<<<2048, 256, 0, stream>>>(Z, qlv, ls, os, ws);
  k_dag<<<321, 256, 0, stream>>>(X, Y, Z, qmu, qlv, llv, ls, os, ws, out);
}

// Round 7
// 344.849 us; speedup vs baseline: 1.2840x; 1.2840x over previous
//
#include <hip/hip_runtime.h>
#include <math.h>

#define MI 512
#define NPT 8192
#define JIT 1e-6f
#define LOG2PI 1.8378770664093453f

// ws float offsets
#define OFF_A     0         // 512x512 Kuu -> L (lower; diag blocks never read downstream)
#define OFF_LINV  262144    // 512x512 Linv^T (LT[r][c] = Linv[c][r]); upper region only
#define OFF_QS    524288    // 512x512 q_sqrt
#define OFF_QC    786432    // 512x512 q_cov (symmetric)
#define OFF_DINV  1048576   // 8 x 64x64 diag-block inverses (coherent domain)
#define OFF_PART  1081856   // 512 partial ell sums
#define OFF_FLAGS 1082368   // flags, each padded to 32 uints (128 B)
// flag ids (padded): fD=0..7, FL=8..71 (8+b*8+p), TFLG=72..135 (72+s*8+J),
//                    ROWC=136..143, GFLG=144..207 (144+b*8+p), QCC=208, PARTC=209
#define NFLAGS 211

#define FMA16(ACC,a0,a1,a2,a3,b0,b1,b2,b3) \
  ACC[0][0]+=a0*b0; ACC[0][1]+=a0*b1; ACC[0][2]+=a0*b2; ACC[0][3]+=a0*b3; \
  ACC[1][0]+=a1*b0; ACC[1][1]+=a1*b1; ACC[1][2]+=a1*b2; ACC[1][3]+=a1*b3; \
  ACC[2][0]+=a2*b0; ACC[2][1]+=a2*b1; ACC[2][2]+=a2*b2; ACC[2][3]+=a2*b3; \
  ACC[3][0]+=a3*b0; ACC[3][1]+=a3*b1; ACC[3][2]+=a3*b2; ACC[3][3]+=a3*b3;

typedef float f4 __attribute__((ext_vector_type(4)));

// ---- coherent (L2-bypassing) accesses for the chol-chain handoff domain ----
// Writers go straight to the L3 coherence point (sc0 sc1); readers bypass any
// (possibly stale) L2 copy. This removes the need for agent acquire/release
// fences (buffer_inv / buffer_wbl2) on the serial chain.
__device__ __forceinline__ f4 ld_coh(const float* p) {
  f4 r;
  asm volatile("global_load_dwordx4 %0, %1, off sc0 sc1\n\ts_waitcnt vmcnt(0)"
               : "=v"(r) : "v"(p) : "memory");
  return r;
}
__device__ __forceinline__ void ld_coh4x4(const float* p0, const float* p1,
    const float* p2, const float* p3, f4& a, f4& b, f4& c, f4& d) {
  asm volatile(
    "global_load_dwordx4 %0, %4, off sc0 sc1\n\t"
    "global_load_dwordx4 %1, %5, off sc0 sc1\n\t"
    "global_load_dwordx4 %2, %6, off sc0 sc1\n\t"
    "global_load_dwordx4 %3, %7, off sc0 sc1\n\t"
    "s_waitcnt vmcnt(0)"
    : "=&v"(a), "=&v"(b), "=&v"(c), "=&v"(d)
    : "v"(p0), "v"(p1), "v"(p2), "v"(p3) : "memory");
}
__device__ __forceinline__ void st_coh(float* p, f4 v) {
  asm volatile("global_store_dwordx4 %0, %1, off sc0 sc1" :: "v"(p), "v"(v) : "memory");
}

// fenced protocol (cached data: LT, QC)
__device__ __forceinline__ void wait_flag(unsigned* f, int tid) {
  if (tid == 0) {
    while (__hip_atomic_load(f, __ATOMIC_RELAXED, __HIP_MEMORY_SCOPE_AGENT) == 0)
      __builtin_amdgcn_s_sleep(2);
    __builtin_amdgcn_fence(__ATOMIC_ACQUIRE, "agent");
  }
  __syncthreads();
}
__device__ __forceinline__ void wait_count(unsigned* c, unsigned tgt, int tid) {
  if (tid == 0) {
    while (__hip_atomic_load(c, __ATOMIC_RELAXED, __HIP_MEMORY_SCOPE_AGENT) < tgt)
      __builtin_amdgcn_s_sleep(2);
    __builtin_amdgcn_fence(__ATOMIC_ACQUIRE, "agent");
  }
  __syncthreads();
}
__device__ __forceinline__ void publish_tile(unsigned* f, unsigned* cnt, int tid) {
  __syncthreads();
  if (tid == 0) {
    __builtin_amdgcn_fence(__ATOMIC_RELEASE, "agent");
    __hip_atomic_store(f, 1u, __ATOMIC_RELAXED, __HIP_MEMORY_SCOPE_AGENT);
    __hip_atomic_fetch_add(cnt, 1u, __ATOMIC_RELAXED, __HIP_MEMORY_SCOPE_AGENT);
  }
}
// fence-free protocol (coherent data: A panels, DINV)
__device__ __forceinline__ void wait_flag_nf(unsigned* f, int tid) {
  if (tid == 0)
    while (__hip_atomic_load(f, __ATOMIC_RELAXED, __HIP_MEMORY_SCOPE_AGENT) == 0)
      __builtin_amdgcn_s_sleep(2);
  __syncthreads();
}
__device__ __forceinline__ void raise_flag_nf(unsigned* f, int tid) {
  asm volatile("s_waitcnt vmcnt(0)" ::: "memory");   // each wave drains its sc-stores
  __syncthreads();
  if (tid == 0)
    __hip_atomic_store(f, 1u, __ATOMIC_RELAXED, __HIP_MEMORY_SCOPE_AGENT);
}

#define SCAT65(Sdst, fi, gv) { int r_=(fi)>>4, c_=((fi)&15)*4; \
  Sdst[r_*65+c_+0]=gv.x; Sdst[r_*65+c_+1]=gv.y; Sdst[r_*65+c_+2]=gv.z; Sdst[r_*65+c_+3]=gv.w; }

// ---------------------------------------------------------------- prep
__global__ __launch_bounds__(256) void k_prep(const float* __restrict__ Z,
    const float* __restrict__ qlv, const float* __restrict__ lsP,
    const float* __restrict__ osP, float* __restrict__ ws) {
  int u = blockIdx.x*256 + threadIdx.x;
  if (blockIdx.x < 27) {
    int fi = blockIdx.x*256 + threadIdx.x;
    if (fi < NFLAGS*32) ((unsigned*)(ws + OFF_FLAGS))[fi] = 0u;
  }
  float ls = lsP[0], os = osP[0];
  float ils2 = 1.0f/(ls*ls);
  if (u < MI*MI) {
    int i = u >> 9, j = u & 511;
    float4 a0 = *(const float4*)(Z + i*8);
    float4 a1 = *(const float4*)(Z + i*8 + 4);
    float4 b0 = *(const float4*)(Z + j*8);
    float4 b1 = *(const float4*)(Z + j*8 + 4);
    float d0=a0.x-b0.x, d1=a0.y-b0.y, d2=a0.z-b0.z, d3=a0.w-b0.w;
    float d4=a1.x-b1.x, d5=a1.y-b1.y, d6=a1.z-b1.z, d7=a1.w-b1.w;
    float sq = d0*d0+d1*d1+d2*d2+d3*d3+d4*d4+d5*d5+d6*d6+d7*d7;
    float v = os*__expf(-0.5f*ils2*sq);
    if (i==j) v += JIT;
    ws[OFF_A + u] = v;
  } else {
    int w2 = u - MI*MI;
    if (w2 < MI*MI) {
      int i = w2 >> 9, j = w2 & 511;
      ws[OFF_QS + w2] = (j <= i) ? __expf(0.5f*qlv[w2]) : 0.0f;
    }
  }
}

// -------- fused DAG: chol(8) + linv(36) + gram(21) + qcgemm(64) + main(512) = 641
// __launch_bounds__(256, 3): pin VGPR so 3 blocks/CU co-residency (768 slots
// >= 641 blocks) is guaranteed -> flag-wait DAG cannot deadlock.
__global__ __launch_bounds__(256, 3) void k_dag(const float* __restrict__ X,
    const float* __restrict__ Yv, const float* __restrict__ Z,
    const float* __restrict__ qmu, const float* __restrict__ qlv,
    const float* __restrict__ llvP, const float* __restrict__ lsP,
    const float* __restrict__ osP, float* __restrict__ ws,
    float* __restrict__ out) {
  __shared__ float SH[13340];   // 53.36 KB -> 3 blocks/CU
  float* A    = ws + OFF_A;
  float* LT   = ws + OFF_LINV;
  const float* QC = ws + OFF_QC;
  float* DINV = ws + OFF_DINV;
  float* PART = ws + OFF_PART;
  unsigned* FB = (unsigned*)(ws + OFF_FLAGS);
  #define FLA(i) (FB + (i)*32)
  int bid = blockIdx.x, tid = threadIdx.x;
  int ty4 = (tid >> 4)*4, tx4 = (tid & 15)*4;

  // ================= CHOL path (fence-free coherent handoffs) ============
  if (bid < 8) {
    __builtin_amdgcn_s_setprio(3);
    int b = bid, Rb = b*64;
    float* Dg = SH;            // [64][65] running diag tile
    float* Sa = SH + 4160;     // Dinv staging / assembly
    float* Sb = SH + 8320;     // G / Lsub staging
    float* TMP = SH + 12480;   // 816 floats
    for (int e = tid; e < 4096; e += 256)    // k_prep data: cached read OK
      Dg[(e>>6)*65 + (e&63)] = A[(Rb + (e>>6))*512 + Rb + (e&63)];

    for (int p = 0; p < b; ++p) {
      if (p > 0) wait_flag_nf(FLA(144 + b*8 + p), tid);  // helper wrote G (coh)
      // stage G coherently (overlaps with the fD wait below)
      {
        int f0 = tid, f1 = tid+256, f2 = tid+512, f3 = tid+768;
        f4 g0,g1,g2,g3;
        ld_coh4x4(A + (Rb + (f0>>4))*512 + p*64 + (f0&15)*4,
                  A + (Rb + (f1>>4))*512 + p*64 + (f1&15)*4,
                  A + (Rb + (f2>>4))*512 + p*64 + (f2&15)*4,
                  A + (Rb + (f3>>4))*512 + p*64 + (f3&15)*4, g0,g1,g2,g3);
        SCAT65(Sb, f0, g0) SCAT65(Sb, f1, g1) SCAT65(Sb, f2, g2) SCAT65(Sb, f3, g3)
      }
      wait_flag_nf(FLA(p), tid);                          // fD[p] -> DINV coh-visible
      {
        int f0 = tid, f1 = tid+256, f2 = tid+512, f3 = tid+768;
        f4 d0,d1,d2,d3;
        ld_coh4x4(DINV + p*4096 + f0*4, DINV + p*4096 + f1*4,
                  DINV + p*4096 + f2*4, DINV + p*4096 + f3*4, d0,d1,d2,d3);
        SCAT65(Sa, f0, d0) SCAT65(Sa, f1, d1) SCAT65(Sa, f2, d2) SCAT65(Sa, f3, d3)
      }
      __syncthreads();
      // TRSM: Lsub = G * Dinv_p^T
      float acc2[4][4] = {{0.f}};
      for (int m = 0; m < 64; ++m) {
        float a0=Sb[(ty4+0)*65+m],a1=Sb[(ty4+1)*65+m],a2=Sb[(ty4+2)*65+m],a3=Sb[(ty4+3)*65+m];
        float b0=Sa[(tx4+0)*65+m],b1=Sa[(tx4+1)*65+m],b2=Sa[(tx4+2)*65+m],b3=Sa[(tx4+3)*65+m];
        FMA16(acc2,a0,a1,a2,a3,b0,b1,b2,b3)
      }
      __syncthreads();
      #pragma unroll
      for (int u = 0; u < 4; ++u) {
        f4 lv = {acc2[u][0], acc2[u][1], acc2[u][2], acc2[u][3]};
        st_coh(A + (Rb+ty4+u)*512 + p*64 + tx4, lv);
        Sb[(ty4+u)*65 + tx4+0] = acc2[u][0];
        Sb[(ty4+u)*65 + tx4+1] = acc2[u][1];
        Sb[(ty4+u)*65 + tx4+2] = acc2[u][2];
        Sb[(ty4+u)*65 + tx4+3] = acc2[u][3];
      }
      raise_flag_nf(FLA(8 + b*8 + p), tid);
      // SYRK: Dg -= Lsub Lsub^T
      float c2[4][4] = {{0.f}};
      for (int m = 0; m < 64; ++m) {
        float a0=Sb[(ty4+0)*65+m],a1=Sb[(ty4+1)*65+m],a2=Sb[(ty4+2)*65+m],a3=Sb[(ty4+3)*65+m];
        float b0=Sb[(tx4+0)*65+m],b1=Sb[(tx4+1)*65+m],b2=Sb[(tx4+2)*65+m],b3=Sb[(tx4+3)*65+m];
        FMA16(c2,a0,a1,a2,a3,b0,b1,b2,b3)
      }
      #pragma unroll
      for (int u = 0; u < 4; ++u)
        #pragma unroll
        for (int v = 0; v < 4; ++v)
          Dg[(ty4+u)*65 + tx4+v] -= c2[u][v];
    }
    __syncthreads();

    // factor 64x64 Dg via 16-wide sub-panels; Dinv assembled into Sa
    for (int e = tid; e < 4096; e += 256) Sa[(e>>6)*65 + (e&63)] = 0.0f;
    __syncthreads();
    for (int t = 0; t < 4; ++t) {
      const int c0 = t*16;
      if (tid < 16) {
        float a[16];
        #pragma unroll
        for (int j = 0; j < 16; ++j) a[j] = Dg[(c0+tid)*65 + c0 + j];
        float rr = 0.f;
        #pragma unroll
        for (int j = 0; j < 16; ++j) {
          float d = __shfl(a[j], j);
          float r = rsqrtf(d);
          r = r*(1.5f - 0.5f*d*r*r);
          if (tid == j) rr = r;
          a[j] *= r;
          #pragma unroll
          for (int k = j+1; k < 16; ++k)
            a[k] -= a[j]*__shfl(a[j], k);
        }
        #pragma unroll
        for (int j = 0; j < 16; ++j)
          Dg[(c0+tid)*65 + c0 + j] = (j <= tid) ? a[j] : 0.0f;
        float v[16];
        #pragma unroll
        for (int i = 0; i < 16; ++i) {
          float s = (tid == i) ? 1.0f : 0.0f;
          #pragma unroll
          for (int k = 0; k < i; ++k)
            s -= Dg[(c0+i)*65 + c0 + k]*v[k];
          v[i] = s * __shfl(rr, i);
        }
        #pragma unroll
        for (int i = 0; i < 16; ++i)
          Sa[(c0+i)*65 + c0 + tid] = v[i];
      }
      __syncthreads();
      if (t < 3) {
        const int cnt = 48 - c0;
        const int r0 = c0 + 16;
        float res[3];
        int nout = cnt*16, idx = 0;
        for (int e = tid; e < nout; e += 256, ++idx) {
          int r = r0 + (e >> 4), j = e & 15;
          float s = 0.f;
          #pragma unroll
          for (int m = 0; m < 16; ++m)
            s += Dg[r*65 + c0 + m]*Sa[(c0+j)*65 + c0 + m];
          res[idx] = s;
        }
        __syncthreads();
        idx = 0;
        for (int e = tid; e < nout; e += 256, ++idx)
          Dg[(r0 + (e >> 4))*65 + c0 + (e & 15)] = res[idx];
        __syncthreads();
        for (int e = tid; e < cnt*cnt; e += 256) {
          int r = r0 + e/cnt, c = r0 + e%cnt;
          float s = 0.f;
          #pragma unroll
          for (int m = 0; m < 16; ++m)
            s += Dg[r*65 + c0 + m]*Dg[c*65 + c0 + m];
          Dg[r*65 + c] -= s;
        }
        __syncthreads();
      }
    }
    for (int d = 1; d < 4; ++d) {
      int nout = (4-d)*256;
      for (int e = tid; e < nout; e += 256) {
        int bs = e >> 8, I = bs, J = I + d;
        int i = (e >> 4) & 15, c = e & 15;
        float s = 0.f;
        for (int k = I; k < J; ++k) {
          #pragma unroll
          for (int m = 0; m < 16; ++m)
            s += Dg[(J*16+i)*65 + k*16+m]*Sa[(k*16+m)*65 + I*16+c];
        }
        TMP[bs*272 + i*17 + c] = s;
      }
      __syncthreads();
      for (int e = tid; e < nout; e += 256) {
        int bs = e >> 8, I = bs, J = I + d;
        int i = (e >> 4) & 15, c = e & 15;
        float s = 0.f;
        #pragma unroll
        for (int m = 0; m < 16; ++m)
          s += Sa[(J*16+i)*65 + J*16+m]*TMP[bs*272 + m*17 + c];
        Sa[(J*16+i)*65 + I*16+c] = -s;
      }
      __syncthreads();
    }
    #pragma unroll
    for (int kk = 0; kk < 4; ++kk) {
      int fi = tid + kk*256; int r_ = fi>>4, c_ = (fi&15)*4;
      f4 dv = {Sa[r_*65+c_+0], Sa[r_*65+c_+1], Sa[r_*65+c_+2], Sa[r_*65+c_+3]};
      st_coh(DINV + b*4096 + fi*4, dv);
    }
    raise_flag_nf(FLA(b), tid);
    return;
  }

  // ================= LINV path (36 lower-tri tiles) ======================
  if (bid < 44) {
    __builtin_amdgcn_s_setprio(2);
    int t = bid - 8;
    int s = 0, rem = t;
    while (rem >= s+1) { rem -= (s+1); ++s; }
    int J = rem;
    if (s == J) {
      wait_flag_nf(FLA(s), tid);
      {
        int f0 = tid, f1 = tid+256, f2 = tid+512, f3 = tid+768;
        f4 d0,d1,d2,d3;
        ld_coh4x4(DINV + s*4096 + f0*4, DINV + s*4096 + f1*4,
                  DINV + s*4096 + f2*4, DINV + s*4096 + f3*4, d0,d1,d2,d3);
        #define LTW(fi, dv) { int i_=(fi)>>4, j_=((fi)&15)*4; \
          LT[(64*s+j_+0)*512+64*s+i_]=dv.x; LT[(64*s+j_+1)*512+64*s+i_]=dv.y; \
          LT[(64*s+j_+2)*512+64*s+i_]=dv.z; LT[(64*s+j_+3)*512+64*s+i_]=dv.w; }
        LTW(f0, d0) LTW(f1, d1) LTW(f2, d2) LTW(f3, d3)
      }
      publish_tile(FLA(72 + s*8 + J), FLA(136 + s), tid);   // LT cached: keep release
      return;
    }
    float* Ls = SH;
    float* Vs = SH + 4160;
    float* T  = SH + 8320;
    float acc[4][4] = {{0.f}};
    for (int k = J; k < s; ++k) {
      wait_flag(FLA(72 + k*8 + J), tid);     // TFLG guards LT (cached): fenced
      wait_flag_nf(FLA(8 + s*8 + k), tid);   // FL guards A panel (coherent)
      {
        int f0 = tid, f1 = tid+256, f2 = tid+512, f3 = tid+768;
        f4 a0,a1,a2,a3;
        ld_coh4x4(A + (64*s+(f0>>4))*512 + 64*k + (f0&15)*4,
                  A + (64*s+(f1>>4))*512 + 64*k + (f1&15)*4,
                  A + (64*s+(f2>>4))*512 + 64*k + (f2&15)*4,
                  A + (64*s+(f3>>4))*512 + 64*k + (f3&15)*4, a0,a1,a2,a3);
        #define LSV(fi, av) { int row=(fi)>>4, m4=((fi)&15)*4; \
          Ls[row*65+m4+0]=av.x; Ls[row*65+m4+1]=av.y; Ls[row*65+m4+2]=av.z; Ls[row*65+m4+3]=av.w; \
          float4 v = *(const float4*)(LT + (64*J+row)*512 + 64*k + m4); \
          Vs[(m4+0)*65+row]=v.x; Vs[(m4+1)*65+row]=v.y; Vs[(m4+2)*65+row]=v.z; Vs[(m4+3)*65+row]=v.w; }
        LSV(f0, a0) LSV(f1, a1) LSV(f2, a2) LSV(f3, a3)
      }
      __syncthreads();
      for (int m = 0; m < 64; ++m) {
        float a0=Ls[(ty4+0)*65+m],a1=Ls[(ty4+1)*65+m],a2=Ls[(ty4+2)*65+m],a3=Ls[(ty4+3)*65+m];
        float b0=Vs[m*65+tx4+0],b1=Vs[m*65+tx4+1],b2=Vs[m*65+tx4+2],b3=Vs[m*65+tx4+3];
        FMA16(acc,a0,a1,a2,a3,b0,b1,b2,b3)
      }
      __syncthreads();
    }
    wait_flag_nf(FLA(s), tid);
    #pragma unroll
    for (int u = 0; u < 4; ++u)
      #pragma unroll
      for (int v = 0; v < 4; ++v)
        T[(ty4+u)*65 + tx4+v] = acc[u][v];
    {
      int f0 = tid, f1 = tid+256, f2 = tid+512, f3 = tid+768;
      f4 d0,d1,d2,d3;
      ld_coh4x4(DINV + s*4096 + f0*4, DINV + s*4096 + f1*4,
                DINV + s*4096 + f2*4, DINV + s*4096 + f3*4, d0,d1,d2,d3);
      SCAT65(Ls, f0, d0) SCAT65(Ls, f1, d1) SCAT65(Ls, f2, d2) SCAT65(Ls, f3, d3)
    }
    __syncthreads();
    float acc2[4][4] = {{0.f}};
    for (int m = 0; m < 64; ++m) {
      float a0=Ls[(ty4+0)*65+m],a1=Ls[(ty4+1)*65+m],a2=Ls[(ty4+2)*65+m],a3=Ls[(ty4+3)*65+m];
      float b0=T[m*65+tx4+0],b1=T[m*65+tx4+1],b2=T[m*65+tx4+2],b3=T[m*65+tx4+3];
      FMA16(acc2,a0,a1,a2,a3,b0,b1,b2,b3)
    }
    #pragma unroll
    for (int u = 0; u < 4; ++u)
      #pragma unroll
      for (int v = 0; v < 4; ++v)
        LT[(64*J+tx4+v)*512 + 64*s+ty4+u] = -acc2[u][v];
    publish_tile(FLA(72 + s*8 + J), FLA(136 + s), tid);
    return;
  }

  // ================= GRAM helpers (21 blocks) ============================
  if (bid < 65) {
    __builtin_amdgcn_s_setprio(2);
    int hid = bid - 44;
    int b = 2, rem = hid;
    while (rem >= b-1) { rem -= (b-1); ++b; }
    int p = rem + 1;                       // 1 <= p < b
    float* Sa = SH;                        // [64][65] Lsub(b,pp)
    float* Sb = SH + 4160;                 // [64][65] Lsub(p,pp)
    float gacc[4][4] = {{0.f}};
    for (int pp = 0; pp < p; ++pp) {
      wait_flag_nf(FLA(8 + b*8 + pp), tid);
      wait_flag_nf(FLA(8 + p*8 + pp), tid);
      {
        int f0 = tid, f1 = tid+256, f2 = tid+512, f3 = tid+768;
        f4 a0,a1,a2,a3, b0,b1,b2,b3;
        ld_coh4x4(A + (b*64+(f0>>4))*512 + pp*64 + (f0&15)*4,
                  A + (b*64+(f1>>4))*512 + pp*64 + (f1&15)*4,
                  A + (b*64+(f2>>4))*512 + pp*64 + (f2&15)*4,
                  A + (b*64+(f3>>4))*512 + pp*64 + (f3&15)*4, a0,a1,a2,a3);
        ld_coh4x4(A + (p*64+(f0>>4))*512 + pp*64 + (f0&15)*4,
                  A + (p*64+(f1>>4))*512 + pp*64 + (f1&15)*4,
                  A + (p*64+(f2>>4))*512 + pp*64 + (f2&15)*4,
                  A + (p*64+(f3>>4))*512 + pp*64 + (f3&15)*4, b0,b1,b2,b3);
        SCAT65(Sa, f0, a0) SCAT65(Sa, f1, a1) SCAT65(Sa, f2, a2) SCAT65(Sa, f3, a3)
        SCAT65(Sb, f0, b0) SCAT65(Sb, f1, b1) SCAT65(Sb, f2, b2) SCAT65(Sb, f3, b3)
      }
      __syncthreads();
      for (int m = 0; m < 64; ++m) {
        float a0=Sa[(ty4+0)*65+m],a1=Sa[(ty4+1)*65+m],a2=Sa[(ty4+2)*65+m],a3=Sa[(ty4+3)*65+m];
        float b0=Sb[(tx4+0)*65+m],b1=Sb[(tx4+1)*65+m],b2=Sb[(tx4+2)*65+m],b3=Sb[(tx4+3)*65+m];
        FMA16(gacc,a0,a1,a2,a3,b0,b1,b2,b3)
      }
      __syncthreads();
    }
    {
      float* r0 = A + (b*64+ty4+0)*512 + p*64 + tx4;
      float* r1 = A + (b*64+ty4+1)*512 + p*64 + tx4;
      float* r2 = A + (b*64+ty4+2)*512 + p*64 + tx4;
      float* r3 = A + (b*64+ty4+3)*512 + p*64 + tx4;
      f4 o0,o1,o2,o3;
      ld_coh4x4(r0, r1, r2, r3, o0,o1,o2,o3);
      f4 n0 = {o0.x-gacc[0][0], o0.y-gacc[0][1], o0.z-gacc[0][2], o0.w-gacc[0][3]};
      f4 n1 = {o1.x-gacc[1][0], o1.y-gacc[1][1], o1.z-gacc[1][2], o1.w-gacc[1][3]};
      f4 n2 = {o2.x-gacc[2][0], o2.y-gacc[2][1], o2.z-gacc[2][2], o2.w-gacc[2][3]};
      f4 n3 = {o3.x-gacc[3][0], o3.y-gacc[3][1], o3.z-gacc[3][2], o3.w-gacc[3][3]};
      st_coh(r0, n0); st_coh(r1, n1); st_coh(r2, n2); st_coh(r3, n3);
    }
    raise_flag_nf(FLA(144 + b*8 + p), tid);
    return;
  }

  // ================= QC-GEMM (64 blocks): QC = QS QS^T + JIT*I ===========
  if (bid < 129) {
    __builtin_amdgcn_s_setprio(1);
    int cid = bid - 65;
    int bi = cid >> 3, bj = cid & 7;
    const float* QSp = ws + OFF_QS;
    float* QCw = ws + OFF_QC;
    float* Xs2 = SH;            // [64][20]
    float* Ys2 = SH + 1280;     // [64][20]
    int lrow = tid >> 2, lc4 = (tid & 3)*4;
    float acc[4][4] = {{0.f}};
    for (int kc = 0; kc < 512; kc += 16) {
      float4 xa = *(const float4*)(QSp + (bi*64+lrow)*512 + kc + lc4);
      float4 ya = *(const float4*)(QSp + (bj*64+lrow)*512 + kc + lc4);
      Xs2[lrow*20+lc4+0]=xa.x; Xs2[lrow*20+lc4+1]=xa.y; Xs2[lrow*20+lc4+2]=xa.z; Xs2[lrow*20+lc4+3]=xa.w;
      Ys2[lrow*20+lc4+0]=ya.x; Ys2[lrow*20+lc4+1]=ya.y; Ys2[lrow*20+lc4+2]=ya.z; Ys2[lrow*20+lc4+3]=ya.w;
      __syncthreads();
      #pragma unroll
      for (int kk = 0; kk < 16; ++kk) {
        float a0=Xs2[(ty4+0)*20+kk],a1=Xs2[(ty4+1)*20+kk],a2=Xs2[(ty4+2)*20+kk],a3=Xs2[(ty4+3)*20+kk];
        float b0=Ys2[(tx4+0)*20+kk],b1=Ys2[(tx4+1)*20+kk],b2=Ys2[(tx4+2)*20+kk],b3=Ys2[(tx4+3)*20+kk];
        FMA16(acc,a0,a1,a2,a3,b0,b1,b2,b3)
      }
      __syncthreads();
    }
    #pragma unroll
    for (int u = 0; u < 4; ++u)
      #pragma unroll
      for (int v = 0; v < 4; ++v) {
        int gi = bi*64+ty4+u, gj = bj*64+tx4+v;
        float o = acc[u][v]; if (gi==gj) o += JIT;
        QCw[gi*512+gj] = o;
      }
    __syncthreads();
    if (tid == 0) {
      __builtin_amdgcn_fence(__ATOMIC_RELEASE, "agent");
      __hip_atomic_fetch_add(FLA(208), 1u, __ATOMIC_RELAXED, __HIP_MEMORY_SCOPE_AGENT);
    }
    return;
  }

  // ================= MAIN path (512 blocks, slab-gated, all-thread Lam) ==
  {
    int B = bid - 129;
    float* KL  = SH;            // 8192: k[c][pt] stride 16
    float* PB  = SH + 8192;     // 3264: partial Lam for groups 1..3, [64][17] each
    float* FB2 = SH + 11456;    // 1280: final Lam [64][20] (float4-aligned rows)
    float* qsh = SH + 12736;    // 512
    float* Xs  = SH + 8192;     // overlay PB during KL build (128 floats)
    float* RD  = SH + 8192;     // overlay PB in final reduction (1632 floats)
    float* elli= SH + 9824;     // 16 (after RD)
    int* lastf = (int*)(SH + 13248);
    float ls = lsP[0], os = osP[0], llv = llvP[0];
    float ils2 = 1.0f/(ls*ls);
    if (tid < 128) { int pp = tid>>3, d = tid&7; Xs[pp*8+d] = X[(B*16+pp)*8 + d]; }
    qsh[tid] = qmu[tid]; qsh[tid+256] = qmu[tid+256];
    __syncthreads();
    for (int e = tid; e < 8192; e += 256) {
      int cc = e >> 4, pp = e & 15;
      float4 z0 = *(const float4*)(Z + cc*8);
      float4 z1 = *(const float4*)(Z + cc*8 + 4);
      float d0=z0.x-Xs[pp*8+0], d1=z0.y-Xs[pp*8+1], d2=z0.z-Xs[pp*8+2], d3=z0.w-Xs[pp*8+3];
      float d4=z1.x-Xs[pp*8+4], d5=z1.y-Xs[pp*8+5], d6=z1.z-Xs[pp*8+6], d7=z1.w-Xs[pp*8+7];
      float sq = d0*d0+d1*d1+d2*d2+d3*d3+d4*d4+d5*d5+d6*d6+d7*d7;
      KL[e] = os*__expf(-0.5f*ils2*sq);
    }
    wait_count(FLA(208), 64u, tid);   // QC ready (once, before first PV)

    int gq = tid >> 6;               // c-quarter (wave id)
    int lr = (tid >> 2) & 15;        // row-group within slab (16 x 4 rows)
    int lrow4 = lr*4;
    int pq4 = (tid & 3)*4;           // point group
    int rq4 = (tid >> 2)*4;          // PV output row group (0..252)
    float pmp[4] = {0.f,0.f,0.f,0.f}, lsp[4] = {0.f,0.f,0.f,0.f};
    float ua0[4][4] = {{0.f}}, ua1[4][4] = {{0.f}};

    for (int s = 0; s < 8; ++s) {
      wait_count(FLA(136 + s), (unsigned)(s+1), tid);  // LT col-block s complete
      // ---- Lam slab s: all 256 threads, c-range split 4 ways
      int Q = 16*(s+1);
      int cbeg = gq*Q, cend = cbeg + Q;
      float acc[4][4] = {{0.f}};
      const float* Lcol = LT + 64*s + lrow4;
      #pragma unroll 4
      for (int c = cbeg; c < cend; ++c) {
        float4 kv = *(const float4*)&KL[c*16 + pq4];
        float4 lv = *(const float4*)(Lcol + c*512);
        FMA16(acc, lv.x,lv.y,lv.z,lv.w, kv.x,kv.y,kv.z,kv.w)
      }
      if (gq > 0) {
        float* pb = PB + (gq-1)*1088;
        #pragma unroll
        for (int u = 0; u < 4; ++u)
          #pragma unroll
          for (int v = 0; v < 4; ++v)
            pb[(lrow4+u)*17 + pq4+v] = acc[u][v];
      }
      __syncthreads();
      if (gq == 0) {
        #pragma unroll
        for (int u = 0; u < 4; ++u) {
          float qv = qsh[64*s + lrow4 + u];
          #pragma unroll
          for (int v = 0; v < 4; ++v) {
            float f = acc[u][v]
                    + PB[(lrow4+u)*17 + pq4+v]
                    + PB[1088 + (lrow4+u)*17 + pq4+v]
                    + PB[2176 + (lrow4+u)*17 + pq4+v];
            FB2[(lrow4+u)*20 + pq4+v] = f;
            pmp[v] += f*qv;
            lsp[v] += f*f;
          }
        }
      }
      __syncthreads();
      // ---- PV: ua += QC[64s+cl][:] * Lam[cl][:]
      #pragma unroll 2
      for (int cl = 0; cl < 64; ++cl) {
        float4 kv = *(const float4*)&FB2[cl*20 + pq4];
        float4 q0 = *(const float4*)(QC + (64*s+cl)*512 + rq4);
        float4 q1 = *(const float4*)(QC + (64*s+cl)*512 + 256 + rq4);
        FMA16(ua0, q0.x,q0.y,q0.z,q0.w, kv.x,kv.y,kv.z,kv.w)
        FMA16(ua1, q1.x,q1.y,q1.z,q1.w, kv.x,kv.y,kv.z,kv.w)
      }
    }
    __syncthreads();  // protect PB region before RD overlay

    // ---- final reductions: pm/lsq from group 0 (16 lr-groups), usq from all
    if (gq == 0) {
      #pragma unroll
      for (int v = 0; v < 4; ++v) {
        RD[lr*17 + pq4+v] = pmp[v];
        RD[272 + lr*17 + pq4+v] = lsp[v];
      }
    }
    float usq[4] = {0.f,0.f,0.f,0.f};
    #pragma unroll
    for (int u = 0; u < 4; ++u)
      #pragma unroll
      for (int v = 0; v < 4; ++v)
        usq[v] += ua0[u][v]*ua0[u][v] + ua1[u][v]*ua1[u][v];
    #pragma unroll
    for (int v = 0; v < 4; ++v)
      RD[544 + (tid>>2)*17 + pq4+v] = usq[v];
    __syncthreads();
    if (tid < 16) {
      float pm = 0.f, lq = 0.f, us = 0.f;
      for (int r2 = 0; r2 < 16; ++r2) {
        pm += RD[r2*17 + tid];
        lq += RD[272 + r2*17 + tid];
      }
      for (int r2 = 0; r2 < 64; ++r2)
        us += RD[544 + r2*17 + tid];
      int gi = B*16 + tid;
      float diff = Yv[gi] - pm;
      float diagc = os + us - lq;
      float iss = __expf(-llv);
      elli[tid] = -0.5f*((diff*diff + diagc)*iss + (LOG2PI + llv));
    }
    __syncthreads();
    if (tid == 0) {
      float sum = 0.f;
      #pragma unroll
      for (int i2 = 0; i2 < 16; ++i2) sum += elli[i2];
      PART[B] = sum;
      __builtin_amdgcn_fence(__ATOMIC_RELEASE, "agent");
      unsigned old = __hip_atomic_fetch_add(FLA(209), 1u, __ATOMIC_RELAXED, __HIP_MEMORY_SCOPE_AGENT);
      lastf[0] = (old == 511u) ? 1 : 0;
    }
    __syncthreads();
    if (lastf[0]) {
      // last main block: final scalar fold
      if (tid == 0) __builtin_amdgcn_fence(__ATOMIC_ACQUIRE, "agent");
      __syncthreads();
      double* sh = (double*)SH;   // 256 doubles in the (done) KL region
      double pa = 0.0, tr = 0.0, mm = 0.0, ld = 0.0;
      for (int i = tid; i < 512; i += 256) {
        pa += (double)PART[i];
        tr += (double)QC[i*513];
        double q = (double)qmu[i]; mm += q*q;
        ld += (double)qlv[i*513];
      }
      double vals[4] = {pa, tr, mm, ld};
      double res[4];
      for (int t2 = 0; t2 < 4; ++t2) {
        sh[tid] = vals[t2]; __syncthreads();
        for (int s2 = 128; s2 > 0; s2 >>= 1) {
          if (tid < s2) sh[tid] += sh[tid+s2];
          __syncthreads();
        }
        res[t2] = sh[0]; __syncthreads();
      }
      if (tid == 0) {
        double n = 8192.0;
        double ell = res[0]/n;
        double kl = 0.5*(res[1] + res[2] - 512.0 - res[3])/n;
        out[0] = (float)(ell - kl);
      }
    }
  }
}

extern "C" void kernel_launch(void* const* d_in, const int* in_sizes, int n_in,
                              void* d_out, int out_size, void* d_ws, size_t ws_size,
                              hipStream_t stream) {
  (void)in_sizes; (void)n_in; (void)out_size; (void)ws_size;
  const float* X   = (const float*)d_in[0];
  const float* Y   = (const float*)d_in[1];
  const float* Z   = (const float*)d_in[2];
  const float* qmu = (const float*)d_in[3];
  const float* qlv = (const float*)d_in[4];
  const float* llv = (const float*)d_in[5];
  const float* ls  = (const float*)d_in[6];
  const float* os  = (const float*)d_in[7];
  float* ws = (float*)d_ws;
  float* out = (float*)d_out;

  k_prep<<<2048, 256, 0, stream>>>(Z, qlv, ls, os, ws);
  k_dag<<<641, 256, 0, stream>>>(X, Y, Z, qmu, qlv, llv, ls, os, ws, out);
}